// Round 4
// baseline (313.235 us; speedup 1.0000x reference)
//
#include <hip/hip_runtime.h>
#include <hip/hip_bf16.h>
#include <math.h>

typedef __hip_bfloat16 hbf16;
typedef __attribute__((ext_vector_type(8))) __bf16    bf16x8;
typedef __attribute__((ext_vector_type(4))) float     f32x4;
typedef __attribute__((ext_vector_type(4))) _Float16  f16x4;
typedef __attribute__((ext_vector_type(8))) unsigned short u16x8;

#define C_    1024
#define NTOK  256
#define NH    16
#define J3    3072

__device__ __forceinline__ unsigned short fbits(float v){
    return __builtin_bit_cast(unsigned short, __float2bfloat16(v));
}
__device__ __forceinline__ __bf16 to_bf(float v){
    return __builtin_bit_cast(__bf16, __float2bfloat16(v));
}

__device__ __forceinline__ void gload_lds16(const __bf16* g, __bf16* l) {
    __builtin_amdgcn_global_load_lds((const __attribute__((address_space(1))) void*)g,
                                     (__attribute__((address_space(3))) void*)l, 16, 0, 0);
}

// ---------------------------------------------------------------------------
// cvt both weight tensors in one launch. blocks [0,3072) -> w_qkv, rest -> w_lin
// ---------------------------------------------------------------------------
__global__ __launch_bounds__(256) void cvt_w(const float* __restrict__ wq,
                                             __bf16* __restrict__ wqo,
                                             const float* __restrict__ wl,
                                             __bf16* __restrict__ wlo) {
    const float* in; __bf16* out; int i;
    if (blockIdx.x < 3072) { in = wq; out = wqo; i = blockIdx.x * 256 + threadIdx.x; }
    else                   { in = wl; out = wlo; i = (blockIdx.x - 3072) * 256 + threadIdx.x; }
    float4 v = ((const float4*)in)[i];
    ushort4 u;
    u.x = fbits(v.x); u.y = fbits(v.y); u.z = fbits(v.z); u.w = fbits(v.w);
    ((ushort4*)out)[i] = u;
}

// ---------------------------------------------------------------------------
// xpose_x: X[64,1024,256] f32 -> Xt[b*256+s][k] bf16   (32x32 LDS tiles)
// ---------------------------------------------------------------------------
__global__ __launch_bounds__(256) void xpose_x(const float* __restrict__ X,
                                               __bf16* __restrict__ Xt) {
    __shared__ float t[32][36];
    const int b = blockIdx.z, k0 = blockIdx.y * 32, s0 = blockIdx.x * 32;
    const int tid = threadIdx.x;
    {
        int kl = tid >> 3, s4 = (tid & 7) * 4;
        float4 v = *(const float4*)(X + ((size_t)b << 18) + (size_t)(k0 + kl) * 256 + s0 + s4);
        t[kl][s4] = v.x; t[kl][s4 + 1] = v.y; t[kl][s4 + 2] = v.z; t[kl][s4 + 3] = v.w;
    }
    __syncthreads();
    {
        int sl = tid >> 3, k4 = (tid & 7) * 4;
        ushort4 u;
        u.x = fbits(t[k4][sl]); u.y = fbits(t[k4 + 1][sl]);
        u.z = fbits(t[k4 + 2][sl]); u.w = fbits(t[k4 + 3][sl]);
        *(ushort4*)(Xt + (size_t)(b * 256 + s0 + sl) * 1024 + k0 + k4) = u;
    }
}

// ---------------------------------------------------------------------------
// gemm256<EPI>: C[m,n] = sum_k A[m,k]*B[n,k] (both k-contiguous bf16, K=1024)
// 256x256 tile, BK=32, 16 waves (4Mx4N, per-wave 64x64, acc=64 VGPR),
// DOUBLE-buffered LDS (64 KiB), 2 barriers/step, counted vmcnt.
// Per step per wave: 8 ds_read_b128 + 16 MFMA + 2 gload_lds — 16 staggered
// waves stream LDS reads underneath MFMAs inside the phase (no lgkmcnt(0),
// no sched pinning between reads and MFMA).
// Schedule (per wave, 2 vmcnt units per stage):
//   prologue: stage(0), stage(1)                       [4 outstanding]
//   step s:   WAITVM(2)  -> stage(s) done              [never 0 mid-loop]
//             BARRIER    -> buf s&1 globally ready
//             read frags, 16 MFMA (lgkm-gated)
//             BARRIER    -> all reads of buf s&1 retired (MFMA issue implies
//                           own reads done; barrier makes it global)
//             stage(s+2) -> buf s&1   (safe: reads proven done)
// EPI=0: C -> bf16 row-major ldc=3072 (Y), LDS-transposed coalesced stores.
// EPI=1: A=Wl (m=oc), B=Ot (n=b*256+s): direct f32 stores out[b][oc][s]+bias.
// ---------------------------------------------------------------------------
#define WAITVM_I(N) asm volatile("s_waitcnt vmcnt(" #N ")" ::: "memory")
#define WAITVM(N) WAITVM_I(N)

#define BARRIER()                                                              \
    __builtin_amdgcn_sched_barrier(0);                                         \
    __builtin_amdgcn_s_barrier();                                              \
    __builtin_amdgcn_sched_barrier(0)

// stage one 16 KiB unit (256 rows x 32 k) of tensor G into LDS at l:
// ONE gload_lds per wave (wave w covers rows w*16..w*16+15).
// Linear LDS dest; read-side swizzle (chunk ^= (row>>1)&3) pre-applied to
// the per-lane GLOBAL source chunk: cg = (lane&3) ^ ((lane>>3)&3).
__device__ __forceinline__ void stage16(const __bf16* __restrict__ G,
                                        __bf16* l, int kk, int wave, int lane) {
    const int rl = lane >> 2;
    const int cg = (lane & 3) ^ ((lane >> 3) & 3);
    const int row = wave * 16 + rl;
    gload_lds16(G + ((size_t)row << 10) + kk + cg * 8, l + wave * 512);
}

// One K-step (BK=32). BUF = S&1 (literal), VM = top-of-step vmcnt.
#define STEP(BUF, S, DOSTG, VM)                                                \
  {                                                                            \
    WAITVM(VM);                                                                \
    BARRIER();                                                                 \
    const __bf16* sa_ = sm.kl[BUF] + aoff;                                     \
    const __bf16* sb_ = sm.kl[BUF] + 8192 + boff;                              \
    bf16x8 afr[4], bfr[4];                                                     \
    _Pragma("unroll") for (int i = 0; i < 4; ++i) {                            \
      afr[i] = *(const bf16x8*)(sa_ + i * 512);                                \
      bfr[i] = *(const bf16x8*)(sb_ + i * 512);                                \
    }                                                                          \
    __builtin_amdgcn_s_setprio(1);                                             \
    _Pragma("unroll") for (int mi = 0; mi < 4; ++mi)                           \
      _Pragma("unroll") for (int ni = 0; ni < 4; ++ni)                         \
        acc[mi][ni] = __builtin_amdgcn_mfma_f32_16x16x32_bf16(                 \
            afr[mi], bfr[ni], acc[mi][ni], 0, 0, 0);                           \
    __builtin_amdgcn_s_setprio(0);                                             \
    BARRIER();                                                                 \
    if (DOSTG) {                                                               \
      stage16(Ab, &sm.kl[BUF][0],    ((S) + 2) << 5, wave, lane);              \
      stage16(Bb, &sm.kl[BUF][8192], ((S) + 2) << 5, wave, lane);              \
    }                                                                          \
  }

template <int EPI>
__global__ __launch_bounds__(1024, 4) void gemm256(const __bf16* __restrict__ A,
                                                   const __bf16* __restrict__ B,
                                                   void* __restrict__ Cout,
                                                   const float* __restrict__ bias) {
    __shared__ union __align__(16) {
        __bf16 kl[2][16384];      // 2 bufs x (A 16KiB | B 16KiB) = 64 KiB
        __bf16 st[128][264];      // 66 KiB epilogue staging
    } sm;

    const int tid  = threadIdx.x;
    const int wave = tid >> 6, lane = tid & 63;
    const int wm = wave >> 2, wn = wave & 3;        // 4 x 4 wave grid
    const int quad = lane >> 4, m = lane & 15;

    // bijective XCD swizzle
    const int wg = blockIdx.x;
    int mb, nb;
    if (EPI == 0) {           // 768 blocks = 8 xcd x (8 mb x 12 nb)
        const int local = wg >> 3;                   // 0..95
        mb = (wg & 7) * 8 + (local & 7);             // 0..63
        nb = local >> 3;                             // 0..11
    } else {                  // 256 blocks = 8 xcd x (4 mb x 8 nb)
        const int local = wg >> 3;                   // 0..31
        mb = local & 3;                              // 0..3
        nb = (wg & 7) * 8 + (local >> 2);            // 0..63
    }
    const int m0 = mb << 8, n0 = nb << 8;

    const __bf16* Ab = A + ((size_t)m0 << 10);
    const __bf16* Bb = B + ((size_t)n0 << 10);

    // per-thread constant fragment offsets (elements).
    // swizzle: phys_chunk = quad ^ ((row>>1)&3); row base mult of 16 =>
    // ((row>>1)&3) == ((m>>1)&3).
    const int pcs  = quad ^ ((m >> 1) & 3);
    const int aoff = (wm * 64 + m) * 32 + pcs * 8;   // + mi*512
    const int boff = (wn * 64 + m) * 32 + pcs * 8;   // + ni*512

    f32x4 acc[4][4] = {};

    // prologue: stage steps 0,1 (2 vmcnt units each per wave)
    stage16(Ab, &sm.kl[0][0],    0,  wave, lane);
    stage16(Bb, &sm.kl[0][8192], 0,  wave, lane);
    stage16(Ab, &sm.kl[1][0],    32, wave, lane);
    stage16(Bb, &sm.kl[1][8192], 32, wave, lane);

    for (int tt = 0; tt < 28; tt += 2) {
        STEP(0, tt + 0, 1, 2)
        STEP(1, tt + 1, 1, 2)
    }
    STEP(0, 28, 1, 2)     // stages step 30
    STEP(1, 29, 1, 2)     // stages step 31
    STEP(0, 30, 0, 2)
    STEP(1, 31, 0, 0)

    if (EPI == 0) {
        // ---- stage 128-row halves through LDS, coalesced bf16x8 stores
        __syncthreads();
        __bf16* Y = (__bf16*)Cout;
        #pragma unroll
        for (int h = 0; h < 2; ++h) {
            if ((wm >> 1) == h) {
                #pragma unroll
                for (int mi = 0; mi < 4; ++mi)
                    #pragma unroll
                    for (int ni = 0; ni < 4; ++ni) {
                        const int r = (wm & 1) * 64 + mi * 16 + quad * 4;
                        const int c = wn * 64 + ni * 16 + m;
                        #pragma unroll
                        for (int j = 0; j < 4; ++j)
                            sm.st[r + j][c] = to_bf(acc[mi][ni][j]);
                    }
            }
            __syncthreads();
            #pragma unroll
            for (int i = 0; i < 4; ++i) {
                const int cid = i * 1024 + tid;
                const int r = cid >> 5, ch = (cid & 31) * 8;
                *(bf16x8*)(Y + (size_t)(m0 + h * 128 + r) * 3072 + n0 + ch) =
                    *(const bf16x8*)&sm.st[r][ch];
            }
            __syncthreads();
        }
    } else {
        // direct scatter of C[m=oc][n=b*256+s] into out[b][oc][s] (+bias)
        float* outp = (float*)Cout;
        const int rbase = m0 + wm * 64 + quad * 4;
        const int nbase = n0 + wn * 64 + m;
        #pragma unroll
        for (int mi = 0; mi < 4; ++mi) {
            float bia[4];
            #pragma unroll
            for (int j = 0; j < 4; ++j) bia[j] = bias[rbase + mi * 16 + j];
            #pragma unroll
            for (int ni = 0; ni < 4; ++ni) {
                const int nn = nbase + ni * 16;
                const size_t base = ((size_t)(nn >> 8) << 18) + (nn & 255);
                #pragma unroll
                for (int j = 0; j < 4; ++j) {
                    const int oc = rbase + mi * 16 + j;
                    outp[base + ((size_t)oc << 8)] = acc[mi][ni][j] + bia[j];
                }
            }
        }
    }
}

// ---------------------------------------------------------------------------
// attn_mfma: 16 waves/block, one token per wave (16 consecutive n of one batch).
// o = (softmax_d(rope(q))*scale · softmax_h(rope(k))^T) · v   via MFMA.
// ---------------------------------------------------------------------------
__global__ __launch_bounds__(1024) void attn_mfma(const __bf16* __restrict__ Y,
                                                  __bf16* __restrict__ Ot) {
    __shared__ union __align__(16) {
        __bf16  v[16][1024];      // per-wave v[16 h][64 e]
        ushort4 ost[256][16];     // [s][slot] row-strips (XOR-swizzled slots)
    } sm;

    const int tid  = threadIdx.x;
    const int wave = tid >> 6, lane = tid & 63;
    const int bb = blockIdx.x >> 4;
    const int n0 = (blockIdx.x & 15) * 16;
    const int n  = n0 + wave;
    const int quad = lane >> 4, m = lane & 15;
    const __bf16* Yt = Y + (size_t)(bb * 256 + n) * J3;

    #pragma unroll
    for (int p = 0; p < 2; ++p) {
        const int h = p * 8 + (lane >> 3), part = lane & 7;
        gload_lds16(Yt + h * 192 + 128 + part * 8, &sm.v[wave][p * 512]);
    }

    bf16x8 qb[2], kb[2];
    #pragma unroll
    for (int st = 0; st < 2; ++st) {
        qb[st] = *(const bf16x8*)(Yt + m * 192 +      st * 32 + quad * 8);
        kb[st] = *(const bf16x8*)(Yt + m * 192 + 64 + st * 32 + quad * 8);
    }
    float qf[16], kf[16];
    #pragma unroll
    for (int st = 0; st < 2; ++st)
        #pragma unroll
        for (int j = 0; j < 8; ++j) {
            qf[st * 8 + j] = (float)qb[st][j];
            kf[st * 8 + j] = (float)kb[st][j];
        }

    const float fn = (float)n;
    #pragma unroll
    for (int j = 0; j < 8; ++j) {
        const float d  = (float)(quad * 8 + j);
        const float th = fn * __expf(-0.28782313662425572f * d);  // n * 10000^(-d/32)
        const float sn = __sinf(th), cn = __cosf(th);
        float a0 = qf[j], a1 = qf[8 + j];
        qf[j]     = a0 * cn - a1 * sn;
        qf[8 + j] = a1 * cn + a0 * sn;
        float b0 = kf[j], b1 = kf[8 + j];
        kf[j]     = b0 * cn - b1 * sn;
        kf[8 + j] = b1 * cn + b0 * sn;
    }

    float qe[16], ls = 0.f;
    #pragma unroll
    for (int i = 0; i < 16; ++i) { qe[i] = __expf(qf[i]); ls += qe[i]; }
    ls += __shfl_xor(ls, 16);
    ls += __shfl_xor(ls, 32);
    const float qinv = 0.125f * __builtin_amdgcn_rcpf(ls);
    bf16x8 qbh[2];
    #pragma unroll
    for (int st = 0; st < 2; ++st)
        #pragma unroll
        for (int j = 0; j < 8; ++j) qbh[st][j] = to_bf(qe[st * 8 + j] * qinv);

    float ke[16], kc[16];
    #pragma unroll
    for (int i = 0; i < 16; ++i) { ke[i] = __expf(kf[i]); kc[i] = ke[i]; }
    #pragma unroll
    for (int msk = 1; msk <= 8; msk <<= 1)
        #pragma unroll
        for (int i = 0; i < 16; ++i) kc[i] += __shfl_xor(kc[i], msk);
    bf16x8 kbh[2];
    #pragma unroll
    for (int st = 0; st < 2; ++st)
        #pragma unroll
        for (int j = 0; j < 8; ++j)
            kbh[st][j] = to_bf(ke[st * 8 + j] * __builtin_amdgcn_rcpf(kc[st * 8 + j]));

    f32x4 Sp = {0.f, 0.f, 0.f, 0.f};
    Sp = __builtin_amdgcn_mfma_f32_16x16x32_bf16(kbh[0], qbh[0], Sp, 0, 0, 0);
    Sp = __builtin_amdgcn_mfma_f32_16x16x32_bf16(kbh[1], qbh[1], Sp, 0, 0, 0);

    __syncthreads();   // drain v DMA before LDS picks

    f32x4 o4[4];
#if __has_builtin(__builtin_amdgcn_mfma_f32_16x16x16f16)
    f16x4 af;
    #pragma unroll
    for (int r = 0; r < 4; ++r) af[r] = (_Float16)Sp[r];
    #pragma unroll
    for (int tile = 0; tile < 4; ++tile) {
        f16x4 bv;
        #pragma unroll
        for (int j = 0; j < 4; ++j)
            bv[j] = (_Float16)(float)sm.v[wave][(quad * 4 + j) * 64 + tile * 16 + m];
        f32x4 z = {0.f, 0.f, 0.f, 0.f};
        o4[tile] = __builtin_amdgcn_mfma_f32_16x16x16f16(af, bv, z, 0, 0, 0);
    }
#else
    bf16x8 a2;
    #pragma unroll
    for (int j = 0; j < 8; ++j) {
        int k = quad * 8 + j;
        int src = ((k & 15) >> 2) * 16 + m;
        float v = __shfl(Sp[k & 3], src, 64);
        a2[j] = (quad < 2) ? to_bf(v) : to_bf(0.f);
    }
    #pragma unroll
    for (int tile = 0; tile < 4; ++tile) {
        bf16x8 bv;
        #pragma unroll
        for (int j = 0; j < 8; ++j) {
            int k = quad * 8 + j;
            int kk = (k < 16) ? k : 0;
            bv[j] = sm.v[wave][kk * 64 + tile * 16 + m];
        }
        f32x4 z = {0.f, 0.f, 0.f, 0.f};
        o4[tile] = __builtin_amdgcn_mfma_f32_16x16x32_bf16(a2, bv, z, 0, 0, 0);
    }
#endif

    __syncthreads();   // v dead; reuse LDS as ost

    #pragma unroll
    for (int r = 0; r < 4; ++r) {
        const int s = m * 16 + quad * 4 + r;
        const int phys = wave ^ (quad * 4 + r) ^ m;
        ushort4 u;
        u.x = fbits(o4[0][r]); u.y = fbits(o4[1][r]);
        u.z = fbits(o4[2][r]); u.w = fbits(o4[3][r]);
        sm.ost[s][phys] = u;
    }
    __syncthreads();

    {
        const int row = tid >> 2;
        const int w0  = (tid & 3) * 4;
        ushort4 u4[4];
        #pragma unroll
        for (int j = 0; j < 4; ++j) {
            const int phys = (w0 + j) ^ (row & 15) ^ (row >> 4);
            u4[j] = sm.ost[row][phys];
        }
        __bf16* dst = Ot + (((size_t)(bb * 256 + row)) << 10) + n0 * 4 + w0 * 4;
        u16x8 a = {u4[0].x, u4[0].y, u4[0].z, u4[0].w, u4[1].x, u4[1].y, u4[1].z, u4[1].w};
        u16x8 b = {u4[2].x, u4[2].y, u4[2].z, u4[2].w, u4[3].x, u4[3].y, u4[3].z, u4[3].w};
        *(u16x8*)dst = a;
        *(u16x8*)(dst + 8) = b;
    }
}

// ---------------------------------------------------------------------------
extern "C" void kernel_launch(void* const* d_in, const int* in_sizes, int n_in,
                              void* d_out, int out_size, void* d_ws, size_t ws_size,
                              hipStream_t stream) {
    const float* x     = (const float*)d_in[0];
    const float* w_qkv = (const float*)d_in[1];
    const float* w_lin = (const float*)d_in[2];
    const float* b_lin = (const float*)d_in[3];
    float* out = (float*)d_out;

    char* ws = (char*)d_ws;
    __bf16* Y    = (__bf16*)ws;                               // 96 MiB [16384,3072]
    __bf16* XtOt = (__bf16*)(ws + (size_t)100663296);         // 32 MiB [16384,1024] (Xt then Ot)
    __bf16* Wqb  = (__bf16*)(ws + (size_t)134217728);         // 6 MiB  [3072,1024]
    __bf16* Wlb  = (__bf16*)(ws + (size_t)140509184);         // 2 MiB  [1024,1024]

    cvt_w<<<4096, 256, 0, stream>>>(w_qkv, Wqb, w_lin, Wlb);
    xpose_x<<<dim3(8, 32, 64), 256, 0, stream>>>(x, XtOt);

    gemm256<0><<<768, 1024, 0, stream>>>(XtOt, Wqb, (void*)Y, nullptr);
    attn_mfma<<<1024, 1024, 0, stream>>>(Y, XtOt);            // Xt dead; reuse as Ot
    gemm256<1><<<256, 1024, 0, stream>>>(Wlb, XtOt, (void*)out, b_lin);
}

// Round 5
// 311.973 us; speedup vs baseline: 1.0040x; 1.0040x over previous
//
#include <hip/hip_runtime.h>
#include <hip/hip_bf16.h>
#include <math.h>

typedef __hip_bfloat16 hbf16;
typedef __attribute__((ext_vector_type(8))) __bf16    bf16x8;
typedef __attribute__((ext_vector_type(4))) float     f32x4;
typedef __attribute__((ext_vector_type(4))) _Float16  f16x4;
typedef __attribute__((ext_vector_type(8))) unsigned short u16x8;

#define C_    1024
#define NTOK  256
#define NH    16
#define J3    3072

__device__ __forceinline__ unsigned short fbits(float v){
    return __builtin_bit_cast(unsigned short, __float2bfloat16(v));
}
__device__ __forceinline__ __bf16 to_bf(float v){
    return __builtin_bit_cast(__bf16, __float2bfloat16(v));
}

__device__ __forceinline__ void gload_lds16(const __bf16* g, __bf16* l) {
    __builtin_amdgcn_global_load_lds((const __attribute__((address_space(1))) void*)g,
                                     (__attribute__((address_space(3))) void*)l, 16, 0, 0);
}

// ---------------------------------------------------------------------------
// cvt both weight tensors in one launch. blocks [0,3072) -> w_qkv, rest -> w_lin
// ---------------------------------------------------------------------------
__global__ __launch_bounds__(256) void cvt_w(const float* __restrict__ wq,
                                             __bf16* __restrict__ wqo,
                                             const float* __restrict__ wl,
                                             __bf16* __restrict__ wlo) {
    const float* in; __bf16* out; int i;
    if (blockIdx.x < 3072) { in = wq; out = wqo; i = blockIdx.x * 256 + threadIdx.x; }
    else                   { in = wl; out = wlo; i = (blockIdx.x - 3072) * 256 + threadIdx.x; }
    float4 v = ((const float4*)in)[i];
    ushort4 u;
    u.x = fbits(v.x); u.y = fbits(v.y); u.z = fbits(v.z); u.w = fbits(v.w);
    ((ushort4*)out)[i] = u;
}

// ---------------------------------------------------------------------------
// xpose_x: X[64,1024,256] f32 -> Xt[b*256+s][k] bf16   (32x32 LDS tiles)
// ---------------------------------------------------------------------------
__global__ __launch_bounds__(256) void xpose_x(const float* __restrict__ X,
                                               __bf16* __restrict__ Xt) {
    __shared__ float t[32][36];
    const int b = blockIdx.z, k0 = blockIdx.y * 32, s0 = blockIdx.x * 32;
    const int tid = threadIdx.x;
    {
        int kl = tid >> 3, s4 = (tid & 7) * 4;
        float4 v = *(const float4*)(X + ((size_t)b << 18) + (size_t)(k0 + kl) * 256 + s0 + s4);
        t[kl][s4] = v.x; t[kl][s4 + 1] = v.y; t[kl][s4 + 2] = v.z; t[kl][s4 + 3] = v.w;
    }
    __syncthreads();
    {
        int sl = tid >> 3, k4 = (tid & 7) * 4;
        ushort4 u;
        u.x = fbits(t[k4][sl]); u.y = fbits(t[k4 + 1][sl]);
        u.z = fbits(t[k4 + 2][sl]); u.w = fbits(t[k4 + 3][sl]);
        *(ushort4*)(Xt + (size_t)(b * 256 + s0 + sl) * 1024 + k0 + k4) = u;
    }
}

// ---------------------------------------------------------------------------
// gemm256<EPI>: C[m,n] = sum_k A[m,k]*B[n,k] (both k-contiguous bf16, K=1024)
// 256x256 tile, BK=32, 16 waves (4Mx4N, per-wave 64x64), double-buffered LDS.
// REG-STAGED (T14): global_load_dwordx4 -> VGPR two tiles ahead; ds_write
// after the read-retire barrier. Compiler emits COUNTED vmcnt before the
// ds_write's register use (2 newer loads stay in flight; never a drain).
// Byte placement in LDS identical to the previous gload_lds scheme (linear
// dest, read-side XOR swizzle pre-applied to the global source chunk).
// XCD mapping: nb-major chunks, each XCD spans <=2 nb values -> B-panel
// working set <=1 MiB, resident in the 4 MiB per-XCD L2 (was 6 MiB thrash).
// EPI=0: C -> bf16 row-major ldc=3072 (Y), LDS-transposed coalesced stores.
// EPI=1: A=Wl (m=oc), B=Ot (n=b*256+s): direct f32 stores out[b][oc][s]+bias.
// ---------------------------------------------------------------------------
#define BARRIER()                                                              \
    __builtin_amdgcn_sched_barrier(0);                                         \
    __builtin_amdgcn_s_barrier();                                              \
    __builtin_amdgcn_sched_barrier(0)

#define LGKM0() asm volatile("s_waitcnt lgkmcnt(0)" ::: "memory")

// per-lane staged 16B: row = wave*16 + (lane>>2); chunk cg pre-swizzled.
__device__ __forceinline__ bf16x8 gld(const __bf16* __restrict__ G,
                                      int kk, int wave, int lane) {
    const int rl = lane >> 2;
    const int cg = (lane & 3) ^ ((lane >> 3) & 3);
    const int row = wave * 16 + rl;
    return *(const bf16x8*)(G + ((size_t)row << 10) + kk + cg * 8);
}
// linear LDS dest (matches gload_lds placement): buf + wave*512 + lane*8
__device__ __forceinline__ void stw(__bf16* buf, int wave, int lane,
                                    bf16x8 va, bf16x8 vb) {
    *(bf16x8*)(buf + wave * 512 + lane * 8) = va;
    *(bf16x8*)(buf + 8192 + wave * 512 + lane * 8) = vb;
}

// One K-step (BK=32). BUF = S&1 (literal). RA/RB: regs holding tile S+2.
// DOW: write tile S+2 (S+2<=31). DOL: load tile S+4 into RA/RB (S+4<=31).
#define STEP(BUF, S, RA, RB, DOW, DOL)                                         \
  {                                                                            \
    const __bf16* sa_ = sm.kl[BUF] + aoff;                                     \
    const __bf16* sb_ = sm.kl[BUF] + 8192 + boff;                              \
    bf16x8 afr[4], bfr[4];                                                     \
    _Pragma("unroll") for (int i = 0; i < 4; ++i) {                            \
      afr[i] = *(const bf16x8*)(sa_ + i * 512);                                \
      bfr[i] = *(const bf16x8*)(sb_ + i * 512);                                \
    }                                                                          \
    __builtin_amdgcn_s_setprio(1);                                             \
    _Pragma("unroll") for (int mi = 0; mi < 4; ++mi)                           \
      _Pragma("unroll") for (int ni = 0; ni < 4; ++ni)                         \
        acc[mi][ni] = __builtin_amdgcn_mfma_f32_16x16x32_bf16(                 \
            afr[mi], bfr[ni], acc[mi][ni], 0, 0, 0);                           \
    __builtin_amdgcn_s_setprio(0);                                             \
    BARRIER();                          /* all reads of BUF retired */         \
    if (DOW) {                                                                 \
      stw(sm.kl[BUF], wave, lane, RA, RB);  /* compiler: counted vmcnt */      \
      if (DOL) {                                                               \
        RA = gld(Ab, ((S) + 4) << 5, wave, lane);                              \
        RB = gld(Bb, ((S) + 4) << 5, wave, lane);                              \
      }                                                                        \
      LGKM0();                                                                 \
    }                                                                          \
    BARRIER();                          /* writes visible */                   \
  }

template <int EPI>
__global__ __launch_bounds__(1024, 2) void gemm256(const __bf16* __restrict__ A,
                                                   const __bf16* __restrict__ B,
                                                   void* __restrict__ Cout,
                                                   const float* __restrict__ bias) {
    __shared__ union __align__(16) {
        __bf16 kl[2][16384];      // 2 bufs x (A 16KiB | B 16KiB) = 64 KiB
        __bf16 st[128][264];      // 66 KiB epilogue staging
    } sm;

    const int tid  = threadIdx.x;
    const int wave = tid >> 6, lane = tid & 63;
    const int wm = wave >> 2, wn = wave & 3;        // 4 x 4 wave grid
    const int quad = lane >> 4, m = lane & 15;

    // XCD-chunked, nb-major mapping: each XCD gets a contiguous slab of the
    // nb-major (nb*NMB + mb) index space -> spans <=2-3 nb values.
    const int wg = blockIdx.x;
    int mb, nb;
    if (EPI == 0) {           // 768 blocks: gg = xcd*96 + local; gg = nb*64+mb
        const int gg = (wg & 7) * 96 + (wg >> 3);
        mb = gg & 63;  nb = gg >> 6;                 // nb 0..11
    } else {                  // 256 blocks: gg = xcd*32 + local; gg = nb*4+mb
        const int gg = (wg & 7) * 32 + (wg >> 3);
        mb = gg & 3;   nb = gg >> 2;                 // nb 0..63
    }
    const int m0 = mb << 8, n0 = nb << 8;

    const __bf16* Ab = A + ((size_t)m0 << 10);
    const __bf16* Bb = B + ((size_t)n0 << 10);

    // per-thread constant fragment offsets (elements).
    // swizzle: phys_chunk = quad ^ ((row>>1)&3); row base mult of 16 =>
    // ((row>>1)&3) == ((m>>1)&3).
    const int pcs  = quad ^ ((m >> 1) & 3);
    const int aoff = (wm * 64 + m) * 32 + pcs * 8;   // + mi*512
    const int boff = (wn * 64 + m) * 32 + pcs * 8;   // + ni*512

    f32x4 acc[4][4] = {};

    // prologue: tiles 0,1 -> LDS; tiles 2,3 in flight in regs
    bf16x8 pa = gld(Ab, 0,  wave, lane), pb = gld(Bb, 0,  wave, lane);
    bf16x8 qa = gld(Ab, 32, wave, lane), qb = gld(Bb, 32, wave, lane);
    stw(sm.kl[0], wave, lane, pa, pb);               // waits pa,pb (vmcnt 2)
    pa = gld(Ab, 64, wave, lane); pb = gld(Bb, 64, wave, lane);
    stw(sm.kl[1], wave, lane, qa, qb);               // waits qa,qb (vmcnt 2)
    qa = gld(Ab, 96, wave, lane); qb = gld(Bb, 96, wave, lane);
    LGKM0();
    BARRIER();

    for (int tt = 0; tt < 28; tt += 2) {
        STEP(0, tt + 0, pa, pb, 1, 1)
        STEP(1, tt + 1, qa, qb, 1, 1)
    }
    STEP(0, 28, pa, pb, 1, 0)    // writes tile 30
    STEP(1, 29, qa, qb, 1, 0)    // writes tile 31
    STEP(0, 30, pa, pb, 0, 0)
    STEP(1, 31, qa, qb, 0, 0)

    if (EPI == 0) {
        // ---- stage 128-row halves through LDS, coalesced bf16x8 stores
        __syncthreads();
        __bf16* Y = (__bf16*)Cout;
        #pragma unroll
        for (int h = 0; h < 2; ++h) {
            if ((wm >> 1) == h) {
                #pragma unroll
                for (int mi = 0; mi < 4; ++mi)
                    #pragma unroll
                    for (int ni = 0; ni < 4; ++ni) {
                        const int r = (wm & 1) * 64 + mi * 16 + quad * 4;
                        const int c = wn * 64 + ni * 16 + m;
                        #pragma unroll
                        for (int j = 0; j < 4; ++j)
                            sm.st[r + j][c] = to_bf(acc[mi][ni][j]);
                    }
            }
            __syncthreads();
            #pragma unroll
            for (int i = 0; i < 4; ++i) {
                const int cid = i * 1024 + tid;
                const int r = cid >> 5, ch = (cid & 31) * 8;
                *(bf16x8*)(Y + (size_t)(m0 + h * 128 + r) * 3072 + n0 + ch) =
                    *(const bf16x8*)&sm.st[r][ch];
            }
            __syncthreads();
        }
    } else {
        // direct scatter of C[m=oc][n=b*256+s] into out[b][oc][s] (+bias)
        float* outp = (float*)Cout;
        const int rbase = m0 + wm * 64 + quad * 4;
        const int nbase = n0 + wn * 64 + m;
        #pragma unroll
        for (int mi = 0; mi < 4; ++mi) {
            float bia[4];
            #pragma unroll
            for (int j = 0; j < 4; ++j) bia[j] = bias[rbase + mi * 16 + j];
            #pragma unroll
            for (int ni = 0; ni < 4; ++ni) {
                const int nn = nbase + ni * 16;
                const size_t base = ((size_t)(nn >> 8) << 18) + (nn & 255);
                #pragma unroll
                for (int j = 0; j < 4; ++j) {
                    const int oc = rbase + mi * 16 + j;
                    outp[base + ((size_t)oc << 8)] = acc[mi][ni][j] + bia[j];
                }
            }
        }
    }
}

// ---------------------------------------------------------------------------
// attn_mfma: 16 waves/block, one token per wave (16 consecutive n of one batch).
// o = (softmax_d(rope(q))*scale · softmax_h(rope(k))^T) · v   via MFMA.
// ---------------------------------------------------------------------------
__global__ __launch_bounds__(1024) void attn_mfma(const __bf16* __restrict__ Y,
                                                  __bf16* __restrict__ Ot) {
    __shared__ union __align__(16) {
        __bf16  v[16][1024];      // per-wave v[16 h][64 e]
        ushort4 ost[256][16];     // [s][slot] row-strips (XOR-swizzled slots)
    } sm;

    const int tid  = threadIdx.x;
    const int wave = tid >> 6, lane = tid & 63;
    const int bb = blockIdx.x >> 4;
    const int n0 = (blockIdx.x & 15) * 16;
    const int n  = n0 + wave;
    const int quad = lane >> 4, m = lane & 15;
    const __bf16* Yt = Y + (size_t)(bb * 256 + n) * J3;

    #pragma unroll
    for (int p = 0; p < 2; ++p) {
        const int h = p * 8 + (lane >> 3), part = lane & 7;
        gload_lds16(Yt + h * 192 + 128 + part * 8, &sm.v[wave][p * 512]);
    }

    bf16x8 qb[2], kb[2];
    #pragma unroll
    for (int st = 0; st < 2; ++st) {
        qb[st] = *(const bf16x8*)(Yt + m * 192 +      st * 32 + quad * 8);
        kb[st] = *(const bf16x8*)(Yt + m * 192 + 64 + st * 32 + quad * 8);
    }
    float qf[16], kf[16];
    #pragma unroll
    for (int st = 0; st < 2; ++st)
        #pragma unroll
        for (int j = 0; j < 8; ++j) {
            qf[st * 8 + j] = (float)qb[st][j];
            kf[st * 8 + j] = (float)kb[st][j];
        }

    const float fn = (float)n;
    #pragma unroll
    for (int j = 0; j < 8; ++j) {
        const float d  = (float)(quad * 8 + j);
        const float th = fn * __expf(-0.28782313662425572f * d);  // n * 10000^(-d/32)
        const float sn = __sinf(th), cn = __cosf(th);
        float a0 = qf[j], a1 = qf[8 + j];
        qf[j]     = a0 * cn - a1 * sn;
        qf[8 + j] = a1 * cn + a0 * sn;
        float b0 = kf[j], b1 = kf[8 + j];
        kf[j]     = b0 * cn - b1 * sn;
        kf[8 + j] = b1 * cn + b0 * sn;
    }

    float qe[16], ls = 0.f;
    #pragma unroll
    for (int i = 0; i < 16; ++i) { qe[i] = __expf(qf[i]); ls += qe[i]; }
    ls += __shfl_xor(ls, 16);
    ls += __shfl_xor(ls, 32);
    const float qinv = 0.125f * __builtin_amdgcn_rcpf(ls);
    bf16x8 qbh[2];
    #pragma unroll
    for (int st = 0; st < 2; ++st)
        #pragma unroll
        for (int j = 0; j < 8; ++j) qbh[st][j] = to_bf(qe[st * 8 + j] * qinv);

    float ke[16], kc[16];
    #pragma unroll
    for (int i = 0; i < 16; ++i) { ke[i] = __expf(kf[i]); kc[i] = ke[i]; }
    #pragma unroll
    for (int msk = 1; msk <= 8; msk <<= 1)
        #pragma unroll
        for (int i = 0; i < 16; ++i) kc[i] += __shfl_xor(kc[i], msk);
    bf16x8 kbh[2];
    #pragma unroll
    for (int st = 0; st < 2; ++st)
        #pragma unroll
        for (int j = 0; j < 8; ++j)
            kbh[st][j] = to_bf(ke[st * 8 + j] * __builtin_amdgcn_rcpf(kc[st * 8 + j]));

    f32x4 Sp = {0.f, 0.f, 0.f, 0.f};
    Sp = __builtin_amdgcn_mfma_f32_16x16x32_bf16(kbh[0], qbh[0], Sp, 0, 0, 0);
    Sp = __builtin_amdgcn_mfma_f32_16x16x32_bf16(kbh[1], qbh[1], Sp, 0, 0, 0);

    __syncthreads();   // drain v DMA before LDS picks

    f32x4 o4[4];
#if __has_builtin(__builtin_amdgcn_mfma_f32_16x16x16f16)
    f16x4 af;
    #pragma unroll
    for (int r = 0; r < 4; ++r) af[r] = (_Float16)Sp[r];
    #pragma unroll
    for (int tile = 0; tile < 4; ++tile) {
        f16x4 bv;
        #pragma unroll
        for (int j = 0; j < 4; ++j)
            bv[j] = (_Float16)(float)sm.v[wave][(quad * 4 + j) * 64 + tile * 16 + m];
        f32x4 z = {0.f, 0.f, 0.f, 0.f};
        o4[tile] = __builtin_amdgcn_mfma_f32_16x16x16f16(af, bv, z, 0, 0, 0);
    }
#else
    bf16x8 a2;
    #pragma unroll
    for (int j = 0; j < 8; ++j) {
        int k = quad * 8 + j;
        int src = ((k & 15) >> 2) * 16 + m;
        float v = __shfl(Sp[k & 3], src, 64);
        a2[j] = (quad < 2) ? to_bf(v) : to_bf(0.f);
    }
    #pragma unroll
    for (int tile = 0; tile < 4; ++tile) {
        bf16x8 bv;
        #pragma unroll
        for (int j = 0; j < 8; ++j) {
            int k = quad * 8 + j;
            int kk = (k < 16) ? k : 0;
            bv[j] = sm.v[wave][kk * 64 + tile * 16 + m];
        }
        f32x4 z = {0.f, 0.f, 0.f, 0.f};
        o4[tile] = __builtin_amdgcn_mfma_f32_16x16x32_bf16(a2, bv, z, 0, 0, 0);
    }
#endif

    __syncthreads();   // v dead; reuse LDS as ost

    #pragma unroll
    for (int r = 0; r < 4; ++r) {
        const int s = m * 16 + quad * 4 + r;
        const int phys = wave ^ (quad * 4 + r) ^ m;
        ushort4 u;
        u.x = fbits(o4[0][r]); u.y = fbits(o4[1][r]);
        u.z = fbits(o4[2][r]); u.w = fbits(o4[3][r]);
        sm.ost[s][phys] = u;
    }
    __syncthreads();

    {
        const int row = tid >> 2;
        const int w0  = (tid & 3) * 4;
        ushort4 u4[4];
        #pragma unroll
        for (int j = 0; j < 4; ++j) {
            const int phys = (w0 + j) ^ (row & 15) ^ (row >> 4);
            u4[j] = sm.ost[row][phys];
        }
        __bf16* dst = Ot + (((size_t)(bb * 256 + row)) << 10) + n0 * 4 + w0 * 4;
        u16x8 a = {u4[0].x, u4[0].y, u4[0].z, u4[0].w, u4[1].x, u4[1].y, u4[1].z, u4[1].w};
        u16x8 b = {u4[2].x, u4[2].y, u4[2].z, u4[2].w, u4[3].x, u4[3].y, u4[3].z, u4[3].w};
        *(u16x8*)dst = a;
        *(u16x8*)(dst + 8) = b;
    }
}

// ---------------------------------------------------------------------------
extern "C" void kernel_launch(void* const* d_in, const int* in_sizes, int n_in,
                              void* d_out, int out_size, void* d_ws, size_t ws_size,
                              hipStream_t stream) {
    const float* x     = (const float*)d_in[0];
    const float* w_qkv = (const float*)d_in[1];
    const float* w_lin = (const float*)d_in[2];
    const float* b_lin = (const float*)d_in[3];
    float* out = (float*)d_out;

    char* ws = (char*)d_ws;
    __bf16* Y    = (__bf16*)ws;                               // 96 MiB [16384,3072]
    __bf16* XtOt = (__bf16*)(ws + (size_t)100663296);         // 32 MiB [16384,1024] (Xt then Ot)
    __bf16* Wqb  = (__bf16*)(ws + (size_t)134217728);         // 6 MiB  [3072,1024]
    __bf16* Wlb  = (__bf16*)(ws + (size_t)140509184);         // 2 MiB  [1024,1024]

    cvt_w<<<4096, 256, 0, stream>>>(w_qkv, Wqb, w_lin, Wlb);
    xpose_x<<<dim3(8, 32, 64), 256, 0, stream>>>(x, XtOt);

    gemm256<0><<<768, 1024, 0, stream>>>(XtOt, Wqb, (void*)Y, nullptr);
    attn_mfma<<<1024, 1024, 0, stream>>>(Y, XtOt);            // Xt dead; reuse as Ot
    gemm256<1><<<256, 1024, 0, stream>>>(Wlb, XtOt, (void*)out, b_lin);
}